// Round 1
// baseline (428.658 us; speedup 1.0000x reference)
//
#include <hip/hip_runtime.h>

#define FEAT 128
#define LAT  16

// ---------------- degree count: cnt[d] += 1 per edge ----------------
__global__ void k_count(const int* __restrict__ dst, int E, int* __restrict__ cnt) {
    int e = blockIdx.x * blockDim.x + threadIdx.x;
    if (e < E) atomicAdd(&cnt[dst[e]], 1);
}

// ---- single-block exclusive scan of cnt -> rowstart, plus dinv = rsqrt(cnt+1) ----
__global__ void k_scan(const int* __restrict__ cnt, int* __restrict__ rowstart,
                       float* __restrict__ dinv, int n) {
    __shared__ int part[1024];
    int t = threadIdx.x;
    int per = n / 1024;           // 64
    int base = t * per;
    int s = 0;
    for (int i = 0; i < per; ++i) s += cnt[base + i];
    part[t] = s;
    __syncthreads();
    for (int off = 1; off < 1024; off <<= 1) {
        int v = (t >= off) ? part[t - off] : 0;
        __syncthreads();
        part[t] += v;
        __syncthreads();
    }
    int run = (t == 0) ? 0 : part[t - 1];     // exclusive prefix of this chunk
    for (int i = 0; i < per; ++i) {
        int c = cnt[base + i];
        rowstart[base + i] = run;
        dinv[base + i] = rsqrtf((float)(c + 1));   // +1 self loop
        run += c;
    }
    if (t == 1023) rowstart[n] = run;
}

// ---------------- hs[i][:] = dinv[i] * (x[i] @ W1) ----------------
__global__ void k_hs(const float* __restrict__ x, const float* __restrict__ W1,
                     const float* __restrict__ dinv, float* __restrict__ hs, int n) {
    __shared__ float w[FEAT * LAT];
    int t = threadIdx.x;
    for (int i = t; i < FEAT * LAT; i += blockDim.x) w[i] = W1[i];
    __syncthreads();
    int node = blockIdx.x * blockDim.x + t;
    if (node >= n) return;
    float acc[LAT];
#pragma unroll
    for (int j = 0; j < LAT; ++j) acc[j] = 0.f;
    const float4* xr = (const float4*)(x + (size_t)node * FEAT);
#pragma unroll 4
    for (int k4 = 0; k4 < FEAT / 4; ++k4) {
        float4 xv = xr[k4];
#pragma unroll
        for (int j = 0; j < LAT; ++j) {
            acc[j] += xv.x * w[(4 * k4 + 0) * LAT + j]
                    + xv.y * w[(4 * k4 + 1) * LAT + j]
                    + xv.z * w[(4 * k4 + 2) * LAT + j]
                    + xv.w * w[(4 * k4 + 3) * LAT + j];
        }
    }
    float dv = dinv[node];
    float4* o = (float4*)(hs + (size_t)node * LAT);
#pragma unroll
    for (int q = 0; q < 4; ++q) {
        float4 v;
        v.x = acc[4 * q + 0] * dv; v.y = acc[4 * q + 1] * dv;
        v.z = acc[4 * q + 2] * dv; v.w = acc[4 * q + 3] * dv;
        o[q] = v;
    }
}

// ---------------- CSR fill: csr[rowstart[d] + pos] = src ----------------
__global__ void k_fill(const int* __restrict__ src, const int* __restrict__ dst, int E,
                       const int* __restrict__ rowstart, int* __restrict__ cursor,
                       int* __restrict__ csr) {
    int e = blockIdx.x * blockDim.x + threadIdx.x;
    if (e < E) {
        int d = dst[e];
        int pos = atomicAdd(&cursor[d], 1);
        csr[rowstart[d] + pos] = src[e];
    }
}

// ---- conv1 aggregate (16 lanes per node) + bias + relu + (·W2) + dinv scale ----
__global__ void k_conv1(const float* __restrict__ hs, const int* __restrict__ rowstart,
                        const int* __restrict__ csr, const float* __restrict__ dinv,
                        const float* __restrict__ b1, const float* __restrict__ W2,
                        float* __restrict__ g, int n) {
    int t = threadIdx.x;
    int j = t & 15;
    int node = blockIdx.x * (blockDim.x / 16) + (t >> 4);
    if (node >= n) return;
    int s0 = rowstart[node], s1 = rowstart[node + 1];
    float acc = hs[(size_t)node * LAT + j];          // self loop term
    for (int e = s0; e < s1; ++e) {
        int s = csr[e];                               // broadcast across 16 lanes
        acc += hs[(size_t)s * LAT + j];               // coalesced 64B gather
    }
    float h1 = dinv[node] * acc + b1[j];
    h1 = fmaxf(h1, 0.f);
    float p = h1 * W2[j];
#pragma unroll
    for (int off = 8; off; off >>= 1) p += __shfl_xor(p, off, 16);
    if (j == 0) g[node] = dinv[node] * p;
}

// ---------------- conv2 aggregate (4 lanes per node), scalar ----------------
__global__ void k_conv2(const float* __restrict__ g, const int* __restrict__ rowstart,
                        const int* __restrict__ csr, const float* __restrict__ dinv,
                        const float* __restrict__ b2, float* __restrict__ out, int n) {
    int t = threadIdx.x;
    int q = t & 3;
    int node = blockIdx.x * (blockDim.x / 4) + (t >> 2);
    if (node >= n) return;
    int s0 = rowstart[node], s1 = rowstart[node + 1];
    float acc = (q == 0) ? g[node] : 0.f;             // self loop term
    for (int e = s0 + q; e < s1; e += 4) acc += g[csr[e]];
    acc += __shfl_xor(acc, 1, 4);
    acc += __shfl_xor(acc, 2, 4);
    if (q == 0) out[node] = dinv[node] * acc + b2[0];
}

extern "C" void kernel_launch(void* const* d_in, const int* in_sizes, int n_in,
                              void* d_out, int out_size, void* d_ws, size_t ws_size,
                              hipStream_t stream) {
    const float* x  = (const float*)d_in[0];
    const float* W1 = (const float*)d_in[1];
    const float* b1 = (const float*)d_in[2];
    const float* W2 = (const float*)d_in[3];
    const float* b2 = (const float*)d_in[4];
    const int*   ei = (const int*)d_in[5];

    int n = in_sizes[0] / FEAT;      // 65536 nodes
    int E = in_sizes[5] / 2;         // 2097152 edges
    const int* srcp = ei;
    const int* dstp = ei + E;

    // workspace layout (all 4-byte elements)
    int*   cnt      = (int*)d_ws;                  // n
    int*   cursor   = cnt + n;                     // n
    int*   rowstart = cursor + n;                  // n+1 (pad 64)
    float* dinv     = (float*)(rowstart + n + 64); // n
    float* hs       = dinv + n;                    // n*LAT
    float* g        = hs + (size_t)n * LAT;        // n
    int*   csr      = (int*)(g + n);               // E

    hipMemsetAsync(cnt, 0, (size_t)2 * n * sizeof(int), stream);   // cnt + cursor

    k_count<<<(E + 255) / 256, 256, 0, stream>>>(dstp, E, cnt);
    k_scan <<<1, 1024, 0, stream>>>(cnt, rowstart, dinv, n);
    k_hs   <<<(n + 255) / 256, 256, 0, stream>>>(x, W1, dinv, hs, n);
    k_fill <<<(E + 255) / 256, 256, 0, stream>>>(srcp, dstp, E, rowstart, cursor, csr);
    k_conv1<<<n / 16, 256, 0, stream>>>(hs, rowstart, csr, dinv, b1, W2, g, n);
    k_conv2<<<n / 64, 256, 0, stream>>>(g, rowstart, csr, dinv, b2, (float*)d_out, n);
}

// Round 2
// 184.313 us; speedup vs baseline: 2.3257x; 2.3257x over previous
//
#include <hip/hip_runtime.h>

#define FEAT 128
#define LAT  16
#define NB   256        // buckets = dst >> 8
#define NPB  256        // nodes per bucket (n / NB)

// ---------- P1: bucket histogram over dst ----------
__global__ void k_bhist(const int* __restrict__ dst, int E, int* __restrict__ bcnt) {
    __shared__ int h[NB];
    int t = threadIdx.x;
    h[t] = 0;
    __syncthreads();
    int per = (E + gridDim.x - 1) / gridDim.x;
    int e0 = blockIdx.x * per;
    int e1 = min(e0 + per, E);
    for (int e = e0 + t; e < e1; e += blockDim.x)
        atomicAdd(&h[((unsigned)dst[e]) >> 8], 1);
    __syncthreads();
    if (h[t]) atomicAdd(&bcnt[t], h[t]);
}

// ---------- tiny scan of 256 bucket counts ----------
__global__ void k_bscan(const int* __restrict__ bcnt, int* __restrict__ boff,
                        int* __restrict__ bcur) {
    __shared__ int s[NB];
    int t = threadIdx.x;
    s[t] = bcnt[t];
    __syncthreads();
    for (int off = 1; off < NB; off <<= 1) {
        int v = (t >= off) ? s[t - off] : 0;
        __syncthreads();
        s[t] += v;
        __syncthreads();
    }
    int excl = (t == 0) ? 0 : s[t - 1];
    boff[t] = excl;
    bcur[t] = excl;
    if (t == NB - 1) boff[NB] = s[t];
}

// ---------- P2: partition edges into bucket regions, packed (src<<8)|(dst&255) ----------
__global__ void k_part(const int* __restrict__ src, const int* __restrict__ dst, int E,
                       int* __restrict__ bcur, int* __restrict__ ebuf) {
    __shared__ int h[NB];
    __shared__ int lcur[NB];
    int t = threadIdx.x;
    h[t] = 0;
    __syncthreads();
    int per = (E + gridDim.x - 1) / gridDim.x;
    int e0 = blockIdx.x * per;
    int e1 = min(e0 + per, E);
    for (int e = e0 + t; e < e1; e += blockDim.x)
        atomicAdd(&h[((unsigned)dst[e]) >> 8], 1);
    __syncthreads();
    if (h[t]) lcur[t] = atomicAdd(&bcur[t], h[t]);
    __syncthreads();
    for (int e = e0 + t; e < e1; e += blockDim.x) {
        int d = dst[e];
        int b = ((unsigned)d) >> 8;
        int pos = atomicAdd(&lcur[b], 1);
        ebuf[pos] = (src[e] << 8) | (d & 255);
    }
}

// ---------- P3: per-bucket local CSR build + rowstart + dinv ----------
__global__ void k_csr(const int* __restrict__ ebuf, const int* __restrict__ boff,
                      int* __restrict__ rowstart, float* __restrict__ dinv,
                      int* __restrict__ csr, int n) {
    __shared__ int h[NPB];
    __shared__ int s[NPB];
    __shared__ int cur[NPB];
    int t = threadIdx.x;
    int b = blockIdx.x;
    int e0 = boff[b], e1 = boff[b + 1];
    h[t] = 0;
    __syncthreads();
    for (int e = e0 + t; e < e1; e += blockDim.x)
        atomicAdd(&h[ebuf[e] & 255], 1);
    __syncthreads();
    s[t] = h[t];
    __syncthreads();
    for (int off = 1; off < NPB; off <<= 1) {
        int v = (t >= off) ? s[t - off] : 0;
        __syncthreads();
        s[t] += v;
        __syncthreads();
    }
    int excl = (t == 0) ? 0 : s[t - 1];
    int node = b * NPB + t;
    rowstart[node] = e0 + excl;
    dinv[node] = rsqrtf((float)(h[t] + 1));
    cur[t] = e0 + excl;
    if (b == gridDim.x - 1 && t == blockDim.x - 1) rowstart[n] = e1;
    __syncthreads();
    for (int e = e0 + t; e < e1; e += blockDim.x) {
        int v = ebuf[e];
        int pos = atomicAdd(&cur[v & 255], 1);
        csr[pos] = ((unsigned)v) >> 8;
    }
}

// ---------- hs[i][:] = dinv[i] * (x[i] @ W1) ----------
__global__ void k_hs(const float* __restrict__ x, const float* __restrict__ W1,
                     const float* __restrict__ dinv, float* __restrict__ hs, int n) {
    __shared__ float w[FEAT * LAT];
    int t = threadIdx.x;
    for (int i = t; i < FEAT * LAT; i += blockDim.x) w[i] = W1[i];
    __syncthreads();
    int node = blockIdx.x * blockDim.x + t;
    if (node >= n) return;
    float acc[LAT];
#pragma unroll
    for (int j = 0; j < LAT; ++j) acc[j] = 0.f;
    const float4* xr = (const float4*)(x + (size_t)node * FEAT);
#pragma unroll 4
    for (int k4 = 0; k4 < FEAT / 4; ++k4) {
        float4 xv = xr[k4];
#pragma unroll
        for (int j = 0; j < LAT; ++j) {
            acc[j] += xv.x * w[(4 * k4 + 0) * LAT + j]
                    + xv.y * w[(4 * k4 + 1) * LAT + j]
                    + xv.z * w[(4 * k4 + 2) * LAT + j]
                    + xv.w * w[(4 * k4 + 3) * LAT + j];
        }
    }
    float dv = dinv[node];
    float4* o = (float4*)(hs + (size_t)node * LAT);
#pragma unroll
    for (int q = 0; q < 4; ++q) {
        float4 v;
        v.x = acc[4 * q + 0] * dv; v.y = acc[4 * q + 1] * dv;
        v.z = acc[4 * q + 2] * dv; v.w = acc[4 * q + 3] * dv;
        o[q] = v;
    }
}

// ---- conv1 aggregate (16 lanes per node) + bias + relu + (·W2) + dinv scale ----
__global__ void k_conv1(const float* __restrict__ hs, const int* __restrict__ rowstart,
                        const int* __restrict__ csr, const float* __restrict__ dinv,
                        const float* __restrict__ b1, const float* __restrict__ W2,
                        float* __restrict__ g, int n) {
    int t = threadIdx.x;
    int j = t & 15;
    int node = blockIdx.x * (blockDim.x / 16) + (t >> 4);
    if (node >= n) return;
    int s0 = rowstart[node], s1 = rowstart[node + 1];
    float acc = hs[(size_t)node * LAT + j];          // self loop term
    for (int e = s0; e < s1; ++e) {
        int s = csr[e];                               // broadcast across 16 lanes
        acc += hs[(size_t)s * LAT + j];               // coalesced 64B gather
    }
    float h1 = dinv[node] * acc + b1[j];
    h1 = fmaxf(h1, 0.f);
    float p = h1 * W2[j];
#pragma unroll
    for (int off = 8; off; off >>= 1) p += __shfl_xor(p, off, 16);
    if (j == 0) g[node] = dinv[node] * p;
}

// ---------------- conv2 aggregate (4 lanes per node), scalar ----------------
__global__ void k_conv2(const float* __restrict__ g, const int* __restrict__ rowstart,
                        const int* __restrict__ csr, const float* __restrict__ dinv,
                        const float* __restrict__ b2, float* __restrict__ out, int n) {
    int t = threadIdx.x;
    int q = t & 3;
    int node = blockIdx.x * (blockDim.x / 4) + (t >> 2);
    if (node >= n) return;
    int s0 = rowstart[node], s1 = rowstart[node + 1];
    float acc = (q == 0) ? g[node] : 0.f;             // self loop term
    for (int e = s0 + q; e < s1; e += 4) acc += g[csr[e]];
    acc += __shfl_xor(acc, 1, 4);
    acc += __shfl_xor(acc, 2, 4);
    if (q == 0) out[node] = dinv[node] * acc + b2[0];
}

extern "C" void kernel_launch(void* const* d_in, const int* in_sizes, int n_in,
                              void* d_out, int out_size, void* d_ws, size_t ws_size,
                              hipStream_t stream) {
    const float* x  = (const float*)d_in[0];
    const float* W1 = (const float*)d_in[1];
    const float* b1 = (const float*)d_in[2];
    const float* W2 = (const float*)d_in[3];
    const float* b2 = (const float*)d_in[4];
    const int*   ei = (const int*)d_in[5];

    int n = in_sizes[0] / FEAT;      // 65536 nodes
    int E = in_sizes[5] / 2;         // 2097152 edges
    const int* srcp = ei;
    const int* dstp = ei + E;

    // workspace layout (4-byte elements)
    int*   bcnt     = (int*)d_ws;                    // NB
    int*   boff     = bcnt + NB;                     // NB+1 (pad to 64)
    int*   bcur     = boff + NB + 64;                // NB
    int*   rowstart = bcur + NB;                     // n+1 (pad 64)
    float* dinv     = (float*)(rowstart + n + 64);   // n
    float* hs       = dinv + n;                      // n*LAT
    float* g        = hs + (size_t)n * LAT;          // n
    int*   ebuf     = (int*)(g + n);                 // E
    int*   csr      = ebuf + E;                      // E

    hipMemsetAsync(bcnt, 0, NB * sizeof(int), stream);

    k_bhist<<<256, NB, 0, stream>>>(dstp, E, bcnt);
    k_bscan<<<1, NB, 0, stream>>>(bcnt, boff, bcur);
    k_part <<<128, NB, 0, stream>>>(srcp, dstp, E, bcur, ebuf);
    k_csr  <<<NB, NPB, 0, stream>>>(ebuf, boff, rowstart, dinv, csr, n);
    k_hs   <<<(n + 255) / 256, 256, 0, stream>>>(x, W1, dinv, hs, n);
    k_conv1<<<n / 16, 256, 0, stream>>>(hs, rowstart, csr, dinv, b1, W2, g, n);
    k_conv2<<<n / 64, 256, 0, stream>>>(g, rowstart, csr, dinv, b2, (float*)d_out, n);
}